// Round 8
// baseline (1300.219 us; speedup 1.0000x reference)
//
#include <hip/hip_runtime.h>

#define NN 50000
#define NE 640000

typedef __bf16 bf16x8 __attribute__((ext_vector_type(8)));
typedef short  short8 __attribute__((ext_vector_type(8)));
typedef float  f32x16 __attribute__((ext_vector_type(16)));
typedef float  f32x2  __attribute__((ext_vector_type(2)));
typedef float  f32x4  __attribute__((ext_vector_type(4)));

__device__ __forceinline__ short f2bf(float v) {
  unsigned u = __builtin_bit_cast(unsigned, v);
  u = (u + 0x7FFFu + ((u >> 16) & 1u)) >> 16;   // RNE
  return (short)u;
}
__device__ __forceinline__ short f2bf_hw(float v) {
  return __builtin_bit_cast(short, (__bf16)v);   // gfx950: v_cvt_pk_bf16_f32
}
__device__ __forceinline__ float silu_f(float v) {
  float e = __builtin_amdgcn_exp2f(v * -1.44269504f);
  return v * __builtin_amdgcn_rcpf(1.0f + e);
}
__device__ __forceinline__ bf16x8 ld8(const short* p) {
  return *(const bf16x8*)(p);
}
__device__ __forceinline__ void atomic_add_f(float* p, float v) {
  __hip_atomic_fetch_add(p, v, __ATOMIC_RELAXED, __HIP_MEMORY_SCOPE_AGENT);
}

// ---------------- prep ----------------
// Edge-layer weights: [256 n][280 k]; k<256 = W[k][n]; k==256 = dist-row (L1) or 0;
// k==257 = bias[n]; k>=258 = 0. Biases fold into the GEMM via A cols 256(dist)/257(one).
__global__ void egcl_prep(const float* __restrict__ mw1, const float* __restrict__ mb1,
                          const float* __restrict__ mw2, const float* __restrict__ mb2,
                          const float* __restrict__ tw1, const float* __restrict__ tb1,
                          const float* __restrict__ tw2, const float* __restrict__ tb2,
                          const float* __restrict__ pw1, const float* __restrict__ pw2,
                          const float* __restrict__ strf, const int* __restrict__ rowp,
                          short* __restrict__ w1t, short* __restrict__ w2t,
                          short* __restrict__ t1t, short* __restrict__ t2t,
                          short* __restrict__ p1t, short* __restrict__ p2t,
                          short* __restrict__ strb, int* __restrict__ deg)
{
  const int S0 = 71680, S2 = 98304, S3 = 32768, SS = NN * 128;
  const int total = 4 * S0 + S2 + S3 + SS + NE;
  int stride = gridDim.x * blockDim.x;
  for (int i = blockIdx.x * blockDim.x + threadIdx.x; i < total; i += stride) {
    int j = i;
    if (j < S0) { int n = j / 280, k = j - n * 280;
      float v = (k < 257) ? mw1[k * 256 + n] : ((k == 257) ? mb1[n] : 0.0f);
      w1t[j] = f2bf(v); continue; }
    j -= S0;
    if (j < S0) { int n = j / 280, k = j - n * 280;
      float v = (k < 256) ? mw2[k * 256 + n] : ((k == 257) ? mb2[n] : 0.0f);
      w2t[j] = f2bf(v); continue; }
    j -= S0;
    if (j < S0) { int n = j / 280, k = j - n * 280;
      float v = (k < 256) ? tw1[k * 256 + n] : ((k == 257) ? tb1[n] : 0.0f);
      t1t[j] = f2bf(v); continue; }
    j -= S0;
    if (j < S0) { int n = j / 280, k = j - n * 280;
      float v = (k < 256) ? tw2[k * 256 + n] : ((k == 257) ? tb2[n] : 0.0f);
      t2t[j] = f2bf(v); continue; }
    j -= S0;
    if (j < S2) { int n = j / 384, k = j - n * 384; p1t[j] = f2bf(pw1[k * 256 + n]); continue; }
    j -= S2;
    if (j < S3) { int n = j >> 8, k = j & 255; p2t[j] = f2bf(pw2[k * 128 + n]); continue; }
    j -= S3;
    if (j < SS) { strb[j] = f2bf(strf[j]); continue; }
    j -= SS;
    atomicAdd(deg + rowp[j], 1);
  }
}

// ---------------- exclusive prefix scan of deg -> base (single block) ----------------
__global__ __launch_bounds__(1024)
void egcl_scan(const int* __restrict__ deg, int* __restrict__ base)
{
  __shared__ int wsum[16], wincl[16];
  __shared__ int carry_s;
  const int tid = threadIdx.x, lane = tid & 63, w = tid >> 6;
  if (tid == 0) carry_s = 0;
  __syncthreads();
  for (int start = 0; start < NN; start += 1024) {
    const int i = start + tid;
    int v = (i < NN) ? deg[i] : 0;
    int s = v;
#pragma unroll
    for (int off = 1; off < 64; off <<= 1) {
      int t = __shfl_up(s, off);
      if (lane >= off) s += t;
    }
    if (lane == 63) wsum[w] = s;
    __syncthreads();
    if (w == 0) {
      int u = (lane < 16) ? wsum[lane] : 0;
#pragma unroll
      for (int off = 1; off < 16; off <<= 1) {
        int t = __shfl_up(u, off);
        if (lane >= off) u += t;
      }
      if (lane < 16) wincl[lane] = u;
    }
    __syncthreads();
    const int waveoff = wincl[w] - wsum[w];
    const int carry = carry_s;
    if (i < NN) base[i] = carry + waveoff + s - v;
    __syncthreads();
    if (tid == 0) carry_s = carry + wincl[15];
    __syncthreads();
  }
  if (tid == 0) base[NN] = NE;
}

// ---------------- scatter edge ids into CSR buckets ----------------
__global__ void egcl_scatter(const int* __restrict__ rowp, const int* __restrict__ base,
                             int* __restrict__ cursor, int* __restrict__ eidg)
{
  int stride = gridDim.x * blockDim.x;
  for (int e = blockIdx.x * blockDim.x + threadIdx.x; e < NE; e += stride) {
    int r = rowp[e];
    int pos = base[r] + atomicAdd(cursor + r, 1);
    eidg[pos] = e;
  }
}

// ---------------- edge kernel: 64-edge tiles, 256 thr, unified K=272 GEMM ----------
// 4 waves, wn = wave. Wave computes 64(m=edges) x 64(n) in ONE k-loop:
// acc[2][2] (64 AGPR), a0/a1 shared across both n-halves (A-LDS reads halved).
// Ab: [64][280] bf16; col 256 = dist, col 257 = 1.0, cols 258..279 = 0.
// A-frag: A[m=l32(+32 sm)][k=lh*8+j]; B-frag: B[k=lh*8+j][n=l32] from WT[n][k].
// D-frag: col(n)=l32; row(m)=(reg&3)+8*(reg>>2)+4*lh (+32 sm).
// Epilogue writes silu(acc) directly to LDS after barrier (no pk staging regs).

__device__ __forceinline__ void gemm64u(const short* Ab, const short* __restrict__ WT,
                                        int wn, int lh, int l32, f32x16 acc[2][2])
{
  acc[0][0] = (f32x16)(0.0f); acc[0][1] = (f32x16)(0.0f);
  acc[1][0] = (f32x16)(0.0f); acc[1][1] = (f32x16)(0.0f);
  const short* arow = Ab + l32 * 280 + lh * 8;
  const short* brow = WT + (wn * 64 + l32) * 280 + lh * 8;
#pragma unroll
  for (int ks = 0; ks < 17; ++ks) {
    const int kb = ks * 16;
    bf16x8 a0 = ld8(arow + kb);
    bf16x8 a1 = ld8(arow + 32 * 280 + kb);
    bf16x8 b0 = ld8(brow + kb);
    bf16x8 b1 = ld8(brow + 32 * 280 + kb);
    acc[0][0] = __builtin_amdgcn_mfma_f32_32x32x16_bf16(a0, b0, acc[0][0], 0, 0, 0);
    acc[1][0] = __builtin_amdgcn_mfma_f32_32x32x16_bf16(a1, b0, acc[1][0], 0, 0, 0);
    acc[0][1] = __builtin_amdgcn_mfma_f32_32x32x16_bf16(a0, b1, acc[0][1], 0, 0, 0);
    acc[1][1] = __builtin_amdgcn_mfma_f32_32x32x16_bf16(a1, b1, acc[1][1], 0, 0, 0);
  }
}

__device__ __forceinline__ void epi_direct(short* Ab, const f32x16 acc[2][2],
                                           int wn, int lh, int l32)
{
#pragma unroll
  for (int sn = 0; sn < 2; ++sn) {
    const int n = wn * 64 + sn * 32 + l32;
#pragma unroll
    for (int sm = 0; sm < 2; ++sm) {
      short* dst = Ab + (sm * 32 + 4 * lh) * 280 + n;
#pragma unroll
      for (int reg = 0; reg < 16; ++reg) {
        const int row = (reg & 3) + 8 * (reg >> 2);
        dst[row * 280] = f2bf_hw(silu_f(acc[sm][sn][reg]));
      }
    }
  }
}

__global__ __launch_bounds__(256, 4)
void egcl_edge(const int* __restrict__ eidx, const float* __restrict__ coord,
               const short* __restrict__ strb, const int* __restrict__ eidg,
               const int* __restrict__ base,
               const short* __restrict__ w1t, const short* __restrict__ w2t,
               const short* __restrict__ t1t, const short* __restrict__ t2t,
               const float* __restrict__ tr_w3,
               float* __restrict__ msg_sum, float* __restrict__ trans_sum)
{
  __shared__ short Ab[64 * 280];
  __shared__ int   rs_s[64], cs_s[64], own_s[64];
  __shared__ float cdx_s[64], cdy_s[64], cdz_s[64], gate_s[64];

  const int tid  = threadIdx.x;
  const int lane = tid & 63, wave = tid >> 6;
  const int lh = lane >> 5, l32 = lane & 31;
  const int wn = wave;
  const int p0 = blockIdx.x * 64;
  const int* __restrict__ rowp = eidx;
  const int* __restrict__ colp = eidx + NE;

  if (tid < 64) {
    int e = eidg[p0 + tid];
    int r = rowp[e], c = colp[e];
    rs_s[tid] = r; cs_s[tid] = c;
    const int wstart = p0 + (tid & ~31);           // 32-edge scatter window
    own_s[tid] = (base[r] >= wstart) && (base[r + 1] <= wstart + 32) ? 1 : 0;
    float dx = coord[r * 3 + 0] - coord[c * 3 + 0];
    float dy = coord[r * 3 + 1] - coord[c * 3 + 1];
    float dz = coord[r * 3 + 2] - coord[c * 3 + 2];
    cdx_s[tid] = dx; cdy_s[tid] = dy; cdz_s[tid] = dz;
    short8 d8 = (short8)(short)0;
    d8[0] = f2bf(dx * dx + dy * dy + dz * dz);   // col 256: dist
    d8[1] = f2bf(1.0f);                          // col 257: constant 1 (bias row)
    *(short8*)(Ab + tid * 280 + 256) = d8;
    *(short8*)(Ab + tid * 280 + 264) = (short8)(short)0;
    *(short8*)(Ab + tid * 280 + 272) = (short8)(short)0;
  }
  __syncthreads();
  // stage A cols 0..255 = [str[row] | str[col]] bf16, 16B chunks
#pragma unroll
  for (int it = 0; it < 8; ++it) {
    int i = tid + it * 256;
    int e = i >> 5, cc = i & 31;
    int node = (cc < 16) ? rs_s[e] : cs_s[e];
    short8 v = *(const short8*)(strb + node * 128 + (cc & 15) * 8);
    *(short8*)(Ab + e * 280 + cc * 8) = v;
  }
  __syncthreads();

  f32x16 acc[2][2];

  // ---- L1 ----
  gemm64u(Ab, w1t, wn, lh, l32, acc);
  __syncthreads();
  epi_direct(Ab, acc, wn, lh, l32);
  __syncthreads();

  // ---- L2 -> msg ----
  gemm64u(Ab, w2t, wn, lh, l32, acc);
  __syncthreads();
  epi_direct(Ab, acc, wn, lh, l32);
  __syncthreads();

  // ---- L3 gemm (reads msg) + msg segment-scatter (reads msg) ----
  gemm64u(Ab, t1t, wn, lh, l32, acc);
  {
    const int cp  = tid & 127;      // column pair: cols 2cp, 2cp+1
    const int e0w = (tid >> 7) * 32;
    float run0 = 0.0f, run1 = 0.0f;
    int prev = rs_s[e0w];
    int own  = own_s[e0w];
#pragma unroll 4
    for (int i = 0; i < 32; ++i) {
      const int idx = e0w + i;
      const int r = rs_s[idx];
      unsigned u = *(const unsigned*)(Ab + idx * 280 + cp * 2);
      float lo = __builtin_bit_cast(float, u << 16);
      float hi = __builtin_bit_cast(float, u & 0xFFFF0000u);
      if (r != prev) {
        if (own) {
          f32x2 v; v.x = run0; v.y = run1;
          *((f32x2*)msg_sum + prev * 128 + cp) = v;
        } else {
          atomic_add_f(msg_sum + prev * 256 + cp * 2 + 0, run0);
          atomic_add_f(msg_sum + prev * 256 + cp * 2 + 1, run1);
        }
        run0 = 0.0f; run1 = 0.0f; prev = r; own = own_s[idx];
      }
      run0 += lo; run1 += hi;
    }
    if (own) {
      f32x2 v; v.x = run0; v.y = run1;
      *((f32x2*)msg_sum + prev * 128 + cp) = v;
    } else {
      atomic_add_f(msg_sum + prev * 256 + cp * 2 + 0, run0);
      atomic_add_f(msg_sum + prev * 256 + cp * 2 + 1, run1);
    }
  }
  __syncthreads();
  epi_direct(Ab, acc, wn, lh, l32);
  __syncthreads();

  // ---- L4 ----
  gemm64u(Ab, t2t, wn, lh, l32, acc);
  __syncthreads();
  epi_direct(Ab, acc, wn, lh, l32);
  __syncthreads();

  // ---- gate = T2 @ tr_w3 (vectorized) ----
  {
    const int e = tid >> 2, p = tid & 3;
    const short* ap = Ab + e * 280 + p * 64;
    const float4* wp = (const float4*)(tr_w3 + p * 64);
    float s = 0.0f;
#pragma unroll
    for (int j = 0; j < 8; ++j) {
      bf16x8 av = ld8(ap + j * 8);
      float4 w0 = wp[2 * j], w1 = wp[2 * j + 1];
      s += (float)av[0] * w0.x + (float)av[1] * w0.y + (float)av[2] * w0.z + (float)av[3] * w0.w;
      s += (float)av[4] * w1.x + (float)av[5] * w1.y + (float)av[6] * w1.z + (float)av[7] * w1.w;
    }
    s += __shfl_xor(s, 1);
    s += __shfl_xor(s, 2);
    if (p == 0) gate_s[e] = s;
  }
  __syncthreads();
  // trans segment-reduce by row (3 threads, one per coord component)
  if (tid < 3) {
    const int c = tid;
    float run = 0.0f;
    int prev = rs_s[0];
    for (int i = 0; i < 64; ++i) {
      const int r = rs_s[i];
      if (r != prev) { atomic_add_f(trans_sum + prev * 3 + c, run); run = 0.0f; prev = r; }
      const float cd = (c == 0) ? cdx_s[i] : ((c == 1) ? cdy_s[i] : cdz_s[i]);
      run += cd * gate_s[i];
    }
    atomic_add_f(trans_sum + prev * 3 + c, run);
  }
}

// ---------------- node kernel ----------------
__global__ __launch_bounds__(256, 3)
void egcl_node(const float* __restrict__ strf, const float* __restrict__ coord,
               const short* __restrict__ strb,
               const short* __restrict__ p1t, const short* __restrict__ p2t,
               const float* __restrict__ pb1, const float* __restrict__ pb2,
               const float* __restrict__ msg_sum, const float* __restrict__ trans_sum,
               const int* __restrict__ base, float* __restrict__ out)
{
  __shared__ short Ab[64 * 392];
  const int tid  = threadIdx.x;
  const int lane = tid & 63, wave = tid >> 6;
  const int quad = lane >> 4, l16 = lane & 15;
  const int n0 = blockIdx.x * 64;

#pragma unroll
  for (int it = 0; it < 4; ++it) {          // str cols 0..127
    int i = tid + it * 256;
    int m = i >> 4, c = i & 15;
    int n = n0 + m;
    short8 v = (short8)(short)0;
    if (n < NN) v = *(const short8*)(strb + n * 128 + c * 8);
    *(short8*)(Ab + m * 392 + c * 8) = v;
  }
#pragma unroll
  for (int it = 0; it < 8; ++it) {          // msg_sum cols 128..383
    int i = tid + it * 256;
    int m = i >> 5, c = i & 31;
    int n = n0 + m;
    short8 v = (short8)(short)0;
    if (n < NN) {
      const float* src = msg_sum + n * 256 + c * 8;
#pragma unroll
      for (int j = 0; j < 8; ++j) v[j] = f2bf_hw(src[j]);
    }
    *(short8*)(Ab + m * 392 + 128 + c * 8) = v;
  }
  __syncthreads();

  f32x4 acc[4][4];
#pragma unroll
  for (int nt = 0; nt < 4; ++nt)
#pragma unroll
    for (int mt = 0; mt < 4; ++mt) acc[nt][mt] = (f32x4)(0.0f);
#pragma unroll
  for (int ks = 0; ks < 12; ++ks) {
    const int kb = ks * 32 + quad * 8;
    bf16x8 b[4];
#pragma unroll
    for (int nt = 0; nt < 4; ++nt)
      b[nt] = ld8(p1t + (wave * 64 + nt * 16 + l16) * 384 + kb);
#pragma unroll
    for (int mt = 0; mt < 4; ++mt) {
      bf16x8 a = ld8(Ab + (mt * 16 + l16) * 392 + kb);
#pragma unroll
      for (int nt = 0; nt < 4; ++nt)
        acc[nt][mt] = __builtin_amdgcn_mfma_f32_16x16x32_bf16(a, b[nt], acc[nt][mt], 0, 0, 0);
    }
  }
  __syncthreads();
#pragma unroll
  for (int nt = 0; nt < 4; ++nt) {
    const int n = wave * 64 + nt * 16 + l16;
    const float bn = pb1[n];
#pragma unroll
    for (int mt = 0; mt < 4; ++mt)
#pragma unroll
      for (int r = 0; r < 4; ++r) {
        const int m = mt * 16 + quad * 4 + r;
        Ab[m * 392 + n] = f2bf_hw(silu_f(acc[nt][mt][r] + bn));
      }
  }
  __syncthreads();

  f32x4 a2[2][4];
#pragma unroll
  for (int nt = 0; nt < 2; ++nt)
#pragma unroll
    for (int mt = 0; mt < 4; ++mt) a2[nt][mt] = (f32x4)(0.0f);
#pragma unroll
  for (int ks = 0; ks < 8; ++ks) {
    const int kb = ks * 32 + quad * 8;
    bf16x8 b0 = ld8(p2t + (wave * 32 + l16) * 256 + kb);
    bf16x8 b1 = ld8(p2t + (wave * 32 + 16 + l16) * 256 + kb);
#pragma unroll
    for (int mt = 0; mt < 4; ++mt) {
      bf16x8 a = ld8(Ab + (mt * 16 + l16) * 392 + kb);
      a2[0][mt] = __builtin_amdgcn_mfma_f32_16x16x32_bf16(a, b0, a2[0][mt], 0, 0, 0);
      a2[1][mt] = __builtin_amdgcn_mfma_f32_16x16x32_bf16(a, b1, a2[1][mt], 0, 0, 0);
    }
  }
#pragma unroll
  for (int nt = 0; nt < 2; ++nt) {
    const int c = wave * 32 + nt * 16 + l16;
    const float bc = pb2[c];
#pragma unroll
    for (int mt = 0; mt < 4; ++mt)
#pragma unroll
      for (int r = 0; r < 4; ++r) {
        const int m = mt * 16 + quad * 4 + r;
        const int n = n0 + m;
        if (n < NN) out[n * 128 + c] = strf[n * 128 + c] + a2[nt][mt][r] + bc;
      }
  }
  if (tid < 64) {
    const int n = n0 + tid;
    if (n < NN) {
      float cv = (float)(base[n + 1] - base[n]); if (cv < 1.0f) cv = 1.0f;
      float inv = __builtin_amdgcn_rcpf(cv);
      out[NN * 128 + n * 3 + 0] = coord[n * 3 + 0] + trans_sum[n * 3 + 0] * inv;
      out[NN * 128 + n * 3 + 1] = coord[n * 3 + 1] + trans_sum[n * 3 + 1] * inv;
      out[NN * 128 + n * 3 + 2] = coord[n * 3 + 2] + trans_sum[n * 3 + 2] * inv;
    }
  }
}

extern "C" void kernel_launch(void* const* d_in, const int* in_sizes, int n_in,
                              void* d_out, int out_size, void* d_ws, size_t ws_size,
                              hipStream_t stream)
{
  const int*   eidx   = (const int*)d_in[0];
  const float* strf   = (const float*)d_in[1];
  const float* coord  = (const float*)d_in[2];
  const float* msg_w1 = (const float*)d_in[3];
  const float* msg_b1 = (const float*)d_in[4];
  const float* msg_w2 = (const float*)d_in[5];
  const float* msg_b2 = (const float*)d_in[6];
  const float* tr_w1  = (const float*)d_in[7];
  const float* tr_b1  = (const float*)d_in[8];
  const float* tr_w2  = (const float*)d_in[9];
  const float* tr_b2  = (const float*)d_in[10];
  const float* tr_w3  = (const float*)d_in[11];
  const float* posi_w1 = (const float*)d_in[12];
  const float* posi_b1 = (const float*)d_in[13];
  const float* posi_w2 = (const float*)d_in[14];
  const float* posi_b2 = (const float*)d_in[15];
  float* out = (float*)d_out;

  char* ws = (char*)d_ws;
  float* msg_sum   = (float*)ws;                    // [N,256] f32     (zeroed)
  float* trans_sum = msg_sum + NN * 256;            // [N,3]           (zeroed)
  int*   deg       = (int*)(trans_sum + NN * 3);    // [N]             (zeroed)
  int*   cursor    = deg + NN;                      // [N]             (zeroed)
  int*   base      = cursor + NN;                   // [N+8]
  int*   eidg      = base + NN + 8;                 // [E]
  short* strb = (short*)(eidg + NE);                // [N,128] bf16
  short* w1t  = strb + NN * 128;                    // [256][280]
  short* w2t  = w1t + 71680;
  short* t1t  = w2t + 71680;
  short* t2t  = t1t + 71680;
  short* p1t  = t2t + 71680;                        // [256][384]
  short* p2t  = p1t + 98304;                        // [128][256]

  const int* rowp = eidx;

  (void)hipMemsetAsync(ws, 0, (size_t)(NN * 256 + NN * 3 + NN + NN) * 4, stream);
  egcl_prep<<<2048, 256, 0, stream>>>(msg_w1, msg_b1, msg_w2, msg_b2,
                                      tr_w1, tr_b1, tr_w2, tr_b2,
                                      posi_w1, posi_w2,
                                      strf, rowp, w1t, w2t, t1t, t2t, p1t, p2t, strb, deg);
  egcl_scan<<<1, 1024, 0, stream>>>(deg, base);
  egcl_scatter<<<2560, 256, 0, stream>>>(rowp, base, cursor, eidg);
  egcl_edge<<<NE / 64, 256, 0, stream>>>(eidx, coord, strb, eidg, base,
                                         w1t, w2t, t1t, t2t, tr_w3,
                                         msg_sum, trans_sum);
  egcl_node<<<(NN + 63) / 64, 256, 0, stream>>>(strf, coord, strb, p1t, p2t,
                                                posi_b1, posi_b2,
                                                msg_sum, trans_sum, base, out);
}

// Round 9
// 980.638 us; speedup vs baseline: 1.3259x; 1.3259x over previous
//
#include <hip/hip_runtime.h>

#define NN 50000
#define NE 640000

typedef __bf16 bf16x8 __attribute__((ext_vector_type(8)));
typedef short  short8 __attribute__((ext_vector_type(8)));
typedef float  f32x16 __attribute__((ext_vector_type(16)));
typedef float  f32x2  __attribute__((ext_vector_type(2)));
typedef float  f32x4  __attribute__((ext_vector_type(4)));

__device__ __forceinline__ short f2bf(float v) {
  unsigned u = __builtin_bit_cast(unsigned, v);
  u = (u + 0x7FFFu + ((u >> 16) & 1u)) >> 16;   // RNE
  return (short)u;
}
__device__ __forceinline__ short f2bf_hw(float v) {
  return __builtin_bit_cast(short, (__bf16)v);
}
__device__ __forceinline__ unsigned pack2(float a, float b) {
  return (unsigned)(unsigned short)f2bf_hw(a) | ((unsigned)(unsigned short)f2bf_hw(b) << 16);
}
__device__ __forceinline__ float silu_f(float v) {
  float e = __builtin_amdgcn_exp2f(v * -1.44269504f);
  return v * __builtin_amdgcn_rcpf(1.0f + e);
}
__device__ __forceinline__ bf16x8 ld8(const short* p) {
  return *(const bf16x8*)(p);
}
__device__ __forceinline__ void atomic_add_f(float* p, float v) {
  __hip_atomic_fetch_add(p, v, __ATOMIC_RELAXED, __HIP_MEMORY_SCOPE_AGENT);
}

// ---------------- prep ----------------
// Edge-layer weights: [256 n][280 k]; k<256 = W[k][n]; k==256 = dist-row (L1 only);
// k==257 = bias[n]; k>=258 = 0. Biases fold into GEMM via A cols 256(dist)/257(1.0).
__global__ void egcl_prep(const float* __restrict__ mw1, const float* __restrict__ mb1,
                          const float* __restrict__ mw2, const float* __restrict__ mb2,
                          const float* __restrict__ tw1, const float* __restrict__ tb1,
                          const float* __restrict__ tw2, const float* __restrict__ tb2,
                          const float* __restrict__ pw1, const float* __restrict__ pw2,
                          const float* __restrict__ strf, const int* __restrict__ rowp,
                          short* __restrict__ w1t, short* __restrict__ w2t,
                          short* __restrict__ t1t, short* __restrict__ t2t,
                          short* __restrict__ p1t, short* __restrict__ p2t,
                          short* __restrict__ strb, int* __restrict__ deg)
{
  const int S0 = 71680, S2 = 98304, S3 = 32768, SS = NN * 128;
  const int total = 4 * S0 + S2 + S3 + SS + NE;
  int stride = gridDim.x * blockDim.x;
  for (int i = blockIdx.x * blockDim.x + threadIdx.x; i < total; i += stride) {
    int j = i;
    if (j < S0) { int n = j / 280, k = j - n * 280;
      float v = (k < 257) ? mw1[k * 256 + n] : ((k == 257) ? mb1[n] : 0.0f);
      w1t[j] = f2bf(v); continue; }
    j -= S0;
    if (j < S0) { int n = j / 280, k = j - n * 280;
      float v = (k < 256) ? mw2[k * 256 + n] : ((k == 257) ? mb2[n] : 0.0f);
      w2t[j] = f2bf(v); continue; }
    j -= S0;
    if (j < S0) { int n = j / 280, k = j - n * 280;
      float v = (k < 256) ? tw1[k * 256 + n] : ((k == 257) ? tb1[n] : 0.0f);
      t1t[j] = f2bf(v); continue; }
    j -= S0;
    if (j < S0) { int n = j / 280, k = j - n * 280;
      float v = (k < 256) ? tw2[k * 256 + n] : ((k == 257) ? tb2[n] : 0.0f);
      t2t[j] = f2bf(v); continue; }
    j -= S0;
    if (j < S2) { int n = j / 384, k = j - n * 384; p1t[j] = f2bf(pw1[k * 256 + n]); continue; }
    j -= S2;
    if (j < S3) { int n = j >> 8, k = j & 255; p2t[j] = f2bf(pw2[k * 128 + n]); continue; }
    j -= S3;
    if (j < SS) { strb[j] = f2bf(strf[j]); continue; }
    j -= SS;
    atomicAdd(deg + rowp[j], 1);
  }
}

// ---------------- exclusive prefix scan of deg -> base (single block) ----------------
__global__ __launch_bounds__(1024)
void egcl_scan(const int* __restrict__ deg, int* __restrict__ base)
{
  __shared__ int wsum[16], wincl[16];
  __shared__ int carry_s;
  const int tid = threadIdx.x, lane = tid & 63, w = tid >> 6;
  if (tid == 0) carry_s = 0;
  __syncthreads();
  for (int start = 0; start < NN; start += 1024) {
    const int i = start + tid;
    int v = (i < NN) ? deg[i] : 0;
    int s = v;
#pragma unroll
    for (int off = 1; off < 64; off <<= 1) {
      int t = __shfl_up(s, off);
      if (lane >= off) s += t;
    }
    if (lane == 63) wsum[w] = s;
    __syncthreads();
    if (w == 0) {
      int u = (lane < 16) ? wsum[lane] : 0;
#pragma unroll
      for (int off = 1; off < 16; off <<= 1) {
        int t = __shfl_up(u, off);
        if (lane >= off) u += t;
      }
      if (lane < 16) wincl[lane] = u;
    }
    __syncthreads();
    const int waveoff = wincl[w] - wsum[w];
    const int carry = carry_s;
    if (i < NN) base[i] = carry + waveoff + s - v;
    __syncthreads();
    if (tid == 0) carry_s = carry + wincl[15];
    __syncthreads();
  }
  if (tid == 0) base[NN] = NE;
}

// ---------------- scatter edge ids into CSR buckets ----------------
__global__ void egcl_scatter(const int* __restrict__ rowp, const int* __restrict__ base,
                             int* __restrict__ cursor, int* __restrict__ eidg)
{
  int stride = gridDim.x * blockDim.x;
  for (int e = blockIdx.x * blockDim.x + threadIdx.x; e < NE; e += stride) {
    int r = rowp[e];
    int pos = base[r] + atomicAdd(cursor + r, 1);
    eidg[pos] = e;
  }
}

// ---------------- edge kernel: 64-edge tiles, 256 thr, half-N passes, K=272 -------
// 4 waves, wn = wave. Wave computes 64(m=edges) x 64(n) in TWO 32-n passes:
// acc = f32x16[2] (32 AGPR) + pk staging (32 VGPR) -- the no-spill budget (R6/R7).
// Ab: [64][280] bf16; stride 280 shorts = 140 words === 12 (mod 32): conflict-free
// b128 A-reads (8-lane groups tile all 32 banks). Col 256 = dist, 257 = 1.0.
// A-frag: A[m=l32(+32 sm)][k=lh*8+j]; B-frag: B[k=lh*8+j][n=l32] from WT[n][k].
// D-frag: col(n)=l32; row(m)=(reg&3)+8*(reg>>2)+4*lh (+32 sm).

__device__ __forceinline__ void gemm32(const short* Ab, const short* __restrict__ WT,
                                       int wn, int nh, int lh, int l32,
                                       f32x16 acc[2])
{
  acc[0] = (f32x16)(0.0f); acc[1] = (f32x16)(0.0f);
  const short* arow = Ab + l32 * 280 + lh * 8;
  const short* brow = WT + (wn * 64 + nh * 32 + l32) * 280 + lh * 8;
#pragma unroll
  for (int ks = 0; ks < 17; ++ks) {
    const int kb = ks * 16;
    bf16x8 b  = ld8(brow + kb);
    bf16x8 a0 = ld8(arow + kb);
    bf16x8 a1 = ld8(arow + 32 * 280 + kb);
    acc[0] = __builtin_amdgcn_mfma_f32_32x32x16_bf16(a0, b, acc[0], 0, 0, 0);
    acc[1] = __builtin_amdgcn_mfma_f32_32x32x16_bf16(a1, b, acc[1], 0, 0, 0);
  }
}

__device__ __forceinline__ void comp_pack32(const f32x16 acc[2], unsigned pk[16])
{
#pragma unroll
  for (int sm = 0; sm < 2; ++sm)
#pragma unroll
    for (int j = 0; j < 8; ++j) {
      float v0 = silu_f(acc[sm][2 * j]);
      float v1 = silu_f(acc[sm][2 * j + 1]);
      pk[sm * 8 + j] = pack2(v0, v1);
    }
}

__device__ __forceinline__ void write_pk32(short* Ab, const unsigned pk0[16],
                                           const unsigned pk1[16],
                                           int wn, int lh, int l32)
{
#pragma unroll
  for (int nh = 0; nh < 2; ++nh) {
    const unsigned* pk = nh ? pk1 : pk0;
    const int n = wn * 64 + nh * 32 + l32;
#pragma unroll
    for (int sm = 0; sm < 2; ++sm) {
      short* dst = Ab + (sm * 32 + 4 * lh) * 280 + n;
#pragma unroll
      for (int j = 0; j < 8; ++j) {
        const int row = (j & 1) * 2 + 8 * (j >> 1);   // rows for regs 2j,2j+1
        const unsigned u = pk[sm * 8 + j];
        dst[row * 280]       = (short)(u & 0xFFFFu);
        dst[(row + 1) * 280] = (short)(u >> 16);
      }
    }
  }
}

__global__ __launch_bounds__(256, 4)
void egcl_edge(const int* __restrict__ eidx, const float* __restrict__ coord,
               const short* __restrict__ strb, const int* __restrict__ eidg,
               const int* __restrict__ base,
               const short* __restrict__ w1t, const short* __restrict__ w2t,
               const short* __restrict__ t1t, const short* __restrict__ t2t,
               const float* __restrict__ tr_w3,
               float* __restrict__ msg_sum, float* __restrict__ trans_sum)
{
  __shared__ short Ab[64 * 280];
  __shared__ int   rs_s[64], cs_s[64], own_s[64];
  __shared__ float cdx_s[64], cdy_s[64], cdz_s[64], gate_s[64];

  const int tid  = threadIdx.x;
  const int lane = tid & 63, wave = tid >> 6;
  const int lh = lane >> 5, l32 = lane & 31;
  const int wn = wave;
  const int p0 = blockIdx.x * 64;
  const int* __restrict__ rowp = eidx;
  const int* __restrict__ colp = eidx + NE;

  if (tid < 64) {
    int e = eidg[p0 + tid];
    int r = rowp[e], c = colp[e];
    rs_s[tid] = r; cs_s[tid] = c;
    const int wstart = p0 + (tid & ~31);           // 32-edge scatter window
    own_s[tid] = (base[r] >= wstart) && (base[r + 1] <= wstart + 32) ? 1 : 0;
    float dx = coord[r * 3 + 0] - coord[c * 3 + 0];
    float dy = coord[r * 3 + 1] - coord[c * 3 + 1];
    float dz = coord[r * 3 + 2] - coord[c * 3 + 2];
    cdx_s[tid] = dx; cdy_s[tid] = dy; cdz_s[tid] = dz;
    short8 d8 = (short8)(short)0;
    d8[0] = f2bf(dx * dx + dy * dy + dz * dz);   // col 256: dist
    d8[1] = f2bf(1.0f);                          // col 257: 1.0 (bias row)
    *(short8*)(Ab + tid * 280 + 256) = d8;
    *(short8*)(Ab + tid * 280 + 264) = (short8)(short)0;
    *(short8*)(Ab + tid * 280 + 272) = (short8)(short)0;
  }
  __syncthreads();
  // stage A cols 0..255 = [str[row] | str[col]] bf16, 16B chunks
#pragma unroll
  for (int it = 0; it < 8; ++it) {
    int i = tid + it * 256;
    int e = i >> 5, cc = i & 31;
    int node = (cc < 16) ? rs_s[e] : cs_s[e];
    short8 v = *(const short8*)(strb + node * 128 + (cc & 15) * 8);
    *(short8*)(Ab + e * 280 + cc * 8) = v;
  }
  __syncthreads();

  f32x16 acc[2];
  unsigned pk0[16], pk1[16];

  // ---- L1 ----
  gemm32(Ab, w1t, wn, 0, lh, l32, acc);
  comp_pack32(acc, pk0);
  gemm32(Ab, w1t, wn, 1, lh, l32, acc);
  comp_pack32(acc, pk1);
  __syncthreads();
  write_pk32(Ab, pk0, pk1, wn, lh, l32);
  __syncthreads();

  // ---- L2 -> msg ----
  gemm32(Ab, w2t, wn, 0, lh, l32, acc);
  comp_pack32(acc, pk0);
  gemm32(Ab, w2t, wn, 1, lh, l32, acc);
  comp_pack32(acc, pk1);
  __syncthreads();
  write_pk32(Ab, pk0, pk1, wn, lh, l32);
  __syncthreads();

  // ---- L3 gemm (reads msg) + msg segment-scatter (reads msg) ----
  gemm32(Ab, t1t, wn, 0, lh, l32, acc);
  comp_pack32(acc, pk0);
  gemm32(Ab, t1t, wn, 1, lh, l32, acc);
  comp_pack32(acc, pk1);
  {
    const int cp  = tid & 127;      // column pair: cols 2cp, 2cp+1
    const int e0w = (tid >> 7) * 32;
    float run0 = 0.0f, run1 = 0.0f;
    int prev = rs_s[e0w];
    int own  = own_s[e0w];
#pragma unroll 4
    for (int i = 0; i < 32; ++i) {
      const int idx = e0w + i;
      const int r = rs_s[idx];
      unsigned u = *(const unsigned*)(Ab + idx * 280 + cp * 2);
      float lo = __builtin_bit_cast(float, u << 16);
      float hi = __builtin_bit_cast(float, u & 0xFFFF0000u);
      if (r != prev) {
        if (own) {
          f32x2 v; v.x = run0; v.y = run1;
          *((f32x2*)msg_sum + prev * 128 + cp) = v;
        } else {
          atomic_add_f(msg_sum + prev * 256 + cp * 2 + 0, run0);
          atomic_add_f(msg_sum + prev * 256 + cp * 2 + 1, run1);
        }
        run0 = 0.0f; run1 = 0.0f; prev = r; own = own_s[idx];
      }
      run0 += lo; run1 += hi;
    }
    if (own) {
      f32x2 v; v.x = run0; v.y = run1;
      *((f32x2*)msg_sum + prev * 128 + cp) = v;
    } else {
      atomic_add_f(msg_sum + prev * 256 + cp * 2 + 0, run0);
      atomic_add_f(msg_sum + prev * 256 + cp * 2 + 1, run1);
    }
  }
  __syncthreads();
  write_pk32(Ab, pk0, pk1, wn, lh, l32);
  __syncthreads();

  // ---- L4 ----
  gemm32(Ab, t2t, wn, 0, lh, l32, acc);
  comp_pack32(acc, pk0);
  gemm32(Ab, t2t, wn, 1, lh, l32, acc);
  comp_pack32(acc, pk1);
  __syncthreads();
  write_pk32(Ab, pk0, pk1, wn, lh, l32);
  __syncthreads();

  // ---- gate = T2 @ tr_w3 (vectorized) ----
  {
    const int e = tid >> 2, p = tid & 3;
    const short* ap = Ab + e * 280 + p * 64;
    const float4* wp = (const float4*)(tr_w3 + p * 64);
    float s = 0.0f;
#pragma unroll
    for (int j = 0; j < 8; ++j) {
      bf16x8 av = ld8(ap + j * 8);
      float4 w0 = wp[2 * j], w1 = wp[2 * j + 1];
      s += (float)av[0] * w0.x + (float)av[1] * w0.y + (float)av[2] * w0.z + (float)av[3] * w0.w;
      s += (float)av[4] * w1.x + (float)av[5] * w1.y + (float)av[6] * w1.z + (float)av[7] * w1.w;
    }
    s += __shfl_xor(s, 1);
    s += __shfl_xor(s, 2);
    if (p == 0) gate_s[e] = s;
  }
  __syncthreads();
  // trans segment-reduce by row (3 threads, one per coord component)
  if (tid < 3) {
    const int c = tid;
    float run = 0.0f;
    int prev = rs_s[0];
    for (int i = 0; i < 64; ++i) {
      const int r = rs_s[i];
      if (r != prev) { atomic_add_f(trans_sum + prev * 3 + c, run); run = 0.0f; prev = r; }
      const float cd = (c == 0) ? cdx_s[i] : ((c == 1) ? cdy_s[i] : cdz_s[i]);
      run += cd * gate_s[i];
    }
    atomic_add_f(trans_sum + prev * 3 + c, run);
  }
}

// ---------------- node kernel ----------------
__global__ __launch_bounds__(256, 3)
void egcl_node(const float* __restrict__ strf, const float* __restrict__ coord,
               const short* __restrict__ strb,
               const short* __restrict__ p1t, const short* __restrict__ p2t,
               const float* __restrict__ pb1, const float* __restrict__ pb2,
               const float* __restrict__ msg_sum, const float* __restrict__ trans_sum,
               const int* __restrict__ base, float* __restrict__ out)
{
  __shared__ short Ab[64 * 392];
  const int tid  = threadIdx.x;
  const int lane = tid & 63, wave = tid >> 6;
  const int quad = lane >> 4, l16 = lane & 15;
  const int n0 = blockIdx.x * 64;

#pragma unroll
  for (int it = 0; it < 4; ++it) {          // str cols 0..127
    int i = tid + it * 256;
    int m = i >> 4, c = i & 15;
    int n = n0 + m;
    short8 v = (short8)(short)0;
    if (n < NN) v = *(const short8*)(strb + n * 128 + c * 8);
    *(short8*)(Ab + m * 392 + c * 8) = v;
  }
#pragma unroll
  for (int it = 0; it < 8; ++it) {          // msg_sum cols 128..383
    int i = tid + it * 256;
    int m = i >> 5, c = i & 31;
    int n = n0 + m;
    short8 v = (short8)(short)0;
    if (n < NN) {
      const float* src = msg_sum + n * 256 + c * 8;
#pragma unroll
      for (int j = 0; j < 8; ++j) v[j] = f2bf_hw(src[j]);
    }
    *(short8*)(Ab + m * 392 + 128 + c * 8) = v;
  }
  __syncthreads();

  f32x4 acc[4][4];
#pragma unroll
  for (int nt = 0; nt < 4; ++nt)
#pragma unroll
    for (int mt = 0; mt < 4; ++mt) acc[nt][mt] = (f32x4)(0.0f);
#pragma unroll
  for (int ks = 0; ks < 12; ++ks) {
    const int kb = ks * 32 + quad * 8;
    bf16x8 b[4];
#pragma unroll
    for (int nt = 0; nt < 4; ++nt)
      b[nt] = ld8(p1t + (wave * 64 + nt * 16 + l16) * 384 + kb);
#pragma unroll
    for (int mt = 0; mt < 4; ++mt) {
      bf16x8 a = ld8(Ab + (mt * 16 + l16) * 392 + kb);
#pragma unroll
      for (int nt = 0; nt < 4; ++nt)
        acc[nt][mt] = __builtin_amdgcn_mfma_f32_16x16x32_bf16(a, b[nt], acc[nt][mt], 0, 0, 0);
    }
  }
  __syncthreads();
#pragma unroll
  for (int nt = 0; nt < 4; ++nt) {
    const int n = wave * 64 + nt * 16 + l16;
    const float bn = pb1[n];
#pragma unroll
    for (int mt = 0; mt < 4; ++mt)
#pragma unroll
      for (int r = 0; r < 4; ++r) {
        const int m = mt * 16 + quad * 4 + r;
        Ab[m * 392 + n] = f2bf_hw(silu_f(acc[nt][mt][r] + bn));
      }
  }
  __syncthreads();

  f32x4 a2[2][4];
#pragma unroll
  for (int nt = 0; nt < 2; ++nt)
#pragma unroll
    for (int mt = 0; mt < 4; ++mt) a2[nt][mt] = (f32x4)(0.0f);
#pragma unroll
  for (int ks = 0; ks < 8; ++ks) {
    const int kb = ks * 32 + quad * 8;
    bf16x8 b0 = ld8(p2t + (wave * 32 + l16) * 256 + kb);
    bf16x8 b1 = ld8(p2t + (wave * 32 + 16 + l16) * 256 + kb);
#pragma unroll
    for (int mt = 0; mt < 4; ++mt) {
      bf16x8 a = ld8(Ab + (mt * 16 + l16) * 392 + kb);
      a2[0][mt] = __builtin_amdgcn_mfma_f32_16x16x32_bf16(a, b0, a2[0][mt], 0, 0, 0);
      a2[1][mt] = __builtin_amdgcn_mfma_f32_16x16x32_bf16(a, b1, a2[1][mt], 0, 0, 0);
    }
  }
#pragma unroll
  for (int nt = 0; nt < 2; ++nt) {
    const int c = wave * 32 + nt * 16 + l16;
    const float bc = pb2[c];
#pragma unroll
    for (int mt = 0; mt < 4; ++mt)
#pragma unroll
      for (int r = 0; r < 4; ++r) {
        const int m = mt * 16 + quad * 4 + r;
        const int n = n0 + m;
        if (n < NN) out[n * 128 + c] = strf[n * 128 + c] + a2[nt][mt][r] + bc;
      }
  }
  if (tid < 64) {
    const int n = n0 + tid;
    if (n < NN) {
      float cv = (float)(base[n + 1] - base[n]); if (cv < 1.0f) cv = 1.0f;
      float inv = __builtin_amdgcn_rcpf(cv);
      out[NN * 128 + n * 3 + 0] = coord[n * 3 + 0] + trans_sum[n * 3 + 0] * inv;
      out[NN * 128 + n * 3 + 1] = coord[n * 3 + 1] + trans_sum[n * 3 + 1] * inv;
      out[NN * 128 + n * 3 + 2] = coord[n * 3 + 2] + trans_sum[n * 3 + 2] * inv;
    }
  }
}

extern "C" void kernel_launch(void* const* d_in, const int* in_sizes, int n_in,
                              void* d_out, int out_size, void* d_ws, size_t ws_size,
                              hipStream_t stream)
{
  const int*   eidx   = (const int*)d_in[0];
  const float* strf   = (const float*)d_in[1];
  const float* coord  = (const float*)d_in[2];
  const float* msg_w1 = (const float*)d_in[3];
  const float* msg_b1 = (const float*)d_in[4];
  const float* msg_w2 = (const float*)d_in[5];
  const float* msg_b2 = (const float*)d_in[6];
  const float* tr_w1  = (const float*)d_in[7];
  const float* tr_b1  = (const float*)d_in[8];
  const float* tr_w2  = (const float*)d_in[9];
  const float* tr_b2  = (const float*)d_in[10];
  const float* tr_w3  = (const float*)d_in[11];
  const float* posi_w1 = (const float*)d_in[12];
  const float* posi_b1 = (const float*)d_in[13];
  const float* posi_w2 = (const float*)d_in[14];
  const float* posi_b2 = (const float*)d_in[15];
  float* out = (float*)d_out;

  char* ws = (char*)d_ws;
  float* msg_sum   = (float*)ws;                    // [N,256] f32     (zeroed)
  float* trans_sum = msg_sum + NN * 256;            // [N,3]           (zeroed)
  int*   deg       = (int*)(trans_sum + NN * 3);    // [N]             (zeroed)
  int*   cursor    = deg + NN;                      // [N]             (zeroed)
  int*   base      = cursor + NN;                   // [N+8]
  int*   eidg      = base + NN + 8;                 // [E]
  short* strb = (short*)(eidg + NE);                // [N,128] bf16
  short* w1t  = strb + NN * 128;                    // [256][280]
  short* w2t  = w1t + 71680;
  short* t1t  = w2t + 71680;
  short* t2t  = t1t + 71680;
  short* p1t  = t2t + 71680;                        // [256][384]
  short* p2t  = p1t + 98304;                        // [128][256]

  const int* rowp = eidx;

  (void)hipMemsetAsync(ws, 0, (size_t)(NN * 256 + NN * 3 + NN + NN) * 4, stream);
  egcl_prep<<<2048, 256, 0, stream>>>(msg_w1, msg_b1, msg_w2, msg_b2,
                                      tr_w1, tr_b1, tr_w2, tr_b2,
                                      posi_w1, posi_w2,
                                      strf, rowp, w1t, w2t, t1t, t2t, p1t, p2t, strb, deg);
  egcl_scan<<<1, 1024, 0, stream>>>(deg, base);
  egcl_scatter<<<2560, 256, 0, stream>>>(rowp, base, cursor, eidg);
  egcl_edge<<<NE / 64, 256, 0, stream>>>(eidx, coord, strb, eidg, base,
                                         w1t, w2t, t1t, t2t, tr_w3,
                                         msg_sum, trans_sum);
  egcl_node<<<(NN + 63) / 64, 256, 0, stream>>>(strf, coord, strb, p1t, p2t,
                                                posi_b1, posi_b2,
                                                msg_sum, trans_sum, base, out);
}